// Round 12
// baseline (3040.398 us; speedup 1.0000x reference)
//
// LSTM Seq2Seq persistent kernel, round 12: r10 (best, 2884us) with the
// barrier replaced by r9's per-wave flag protocol (both pieces individually
// HW-validated) and sleep-free single-wave polling.
//
//  - Exchange scope: sc0 sc1 everywhere (L3 coherence point) - the ONLY
//    regime that works (r5/r11 proved sc0-only fails).
//  - Producer: per-wave h stores (packed f16 hi|lo u32) -> per-wave
//    s_waitcnt vmcnt(0) -> lane0 stores flag[g][jm][wv] = tag. No atomic,
//    no pre-signal syncthreads (parallel flag lines, 64B per WG).
//  - Consumer: wave 0 lanes poll all 64 flags (4B each, no sleep; retry
//    period = L3 RT), then __syncthreads releases the WG; stage; compute.
//  - Compute core identical to r10: 16 groups x 16 WGs, wave-private gates
//    (quadrant-interleaved B cols), f16 hi/lo MFMA (3 chains), fast
//    v_exp/v_rcp gates, decoder z/LN/relu/y with flag-based z exchange.

#include <hip/hip_runtime.h>
#include <cmath>

typedef _Float16 f16;
typedef _Float16 f16x8v __attribute__((ext_vector_type(8)));
typedef float f32x4v __attribute__((ext_vector_type(4)));

#define NTHR 256
#define WPG  16

// ---- fast transcendentals ----
__device__ __forceinline__ float fexp2_(float x) {
#if __has_builtin(__builtin_amdgcn_exp2f)
  return __builtin_amdgcn_exp2f(x);
#else
  return exp2f(x);
#endif
}
__device__ __forceinline__ float frcp_(float x) {
#if __has_builtin(__builtin_amdgcn_rcpf)
  return __builtin_amdgcn_rcpf(x);
#else
  return 1.0f / x;
#endif
}
__device__ __forceinline__ float fsigmoid(float x) {
  float xc = fminf(fmaxf(x, -60.f), 60.f);
  return frcp_(1.f + fexp2_(xc * -1.44269504f));
}
__device__ __forceinline__ float ftanh_(float x) {
  float xc = fminf(fmaxf(x, -15.f), 15.f);
  float e = fexp2_(xc * 2.88539008f);     // e^(2x)
  return (e - 1.f) * frcp_(e + 1.f);
}

// ---- L3-coherent primitives (sc0 sc1 - the proven regime) ----
__device__ __forceinline__ void st_sc_u(unsigned* p, unsigned v) {
  asm volatile("global_store_dword %0, %1, off sc0 sc1" :: "v"(p), "v"(v) : "memory");
}
__device__ __forceinline__ void st_sc_f(float* p, float v) {
  asm volatile("global_store_dword %0, %1, off sc0 sc1" :: "v"(p), "v"(v) : "memory");
}
__device__ __forceinline__ void ld64u_sc(const unsigned* p, uint4& a, uint4& b,
                                         uint4& c, uint4& d) {
  asm volatile(
      "global_load_dwordx4 %0, %4, off sc0 sc1\n\t"
      "global_load_dwordx4 %1, %4, off offset:16 sc0 sc1\n\t"
      "global_load_dwordx4 %2, %4, off offset:32 sc0 sc1\n\t"
      "global_load_dwordx4 %3, %4, off offset:48 sc0 sc1\n\t"
      "s_waitcnt vmcnt(0)"
      : "=&v"(a), "=&v"(b), "=&v"(c), "=&v"(d) : "v"(p) : "memory");
}
__device__ __forceinline__ void ld4f_sc(const float* p, float4& a, float4& b,
                                        float4& c, float4& d) {
  asm volatile(
      "global_load_dwordx4 %0, %4, off sc0 sc1\n\t"
      "global_load_dwordx4 %1, %5, off sc0 sc1\n\t"
      "global_load_dwordx4 %2, %6, off sc0 sc1\n\t"
      "global_load_dwordx4 %3, %7, off sc0 sc1\n\t"
      "s_waitcnt vmcnt(0)"
      : "=&v"(a), "=&v"(b), "=&v"(c), "=&v"(d)
      : "v"(p), "v"(p + 1024), "v"(p + 2048), "v"(p + 3072) : "memory");
}

// Per-wave drain + lane0 flag store. flags: 16 u32 (64B) per WG, slot wv.
__device__ __forceinline__ void signal_wave(unsigned* fslot, unsigned tag) {
  asm volatile("s_waitcnt vmcnt(0)" ::: "memory");   // this wave's stores at L3
  if ((threadIdx.x & 63) == 0) st_sc_u(fslot, tag);
}

// Wave 0 polls all 64 flags (lane l -> WG l>>2, wave l&3); sleep-free.
__device__ __forceinline__ void poll_flags(const unsigned* fbase, unsigned tag) {
  const int l = threadIdx.x & 63;
  const unsigned* p = fbase + (l >> 2) * 16 + (l & 3);
  unsigned guard = 0;
  for (;;) {
    unsigned v;
    asm volatile("global_load_dword %0, %1, off sc0 sc1\n\ts_waitcnt vmcnt(0)"
                 : "=v"(v) : "v"(p) : "memory");
    if (__all((int)(v >= tag))) return;
    if (++guard > (1u << 22)) return;   // safety valve (absmax catches corruption)
  }
}

__device__ __forceinline__ unsigned packhl(float v) {
  f16 h = (f16)v;
  f16 lo = (f16)(v - (float)h);
  unsigned short hb, lb;
  __builtin_memcpy(&hb, &h, 2); __builtin_memcpy(&lb, &lo, 2);
  return (unsigned)hb | ((unsigned)lb << 16);
}
__device__ __forceinline__ float unpackf(unsigned u) {
  unsigned short hb = (unsigned short)(u & 0xffffu), lb = (unsigned short)(u >> 16);
  f16 h, l;
  __builtin_memcpy(&h, &hb, 2); __builtin_memcpy(&l, &lb, 2);
  return (float)h + (float)l;
}
__device__ __forceinline__ void unpack_wr(uint4 c, f16* ph, f16* pl) {
  unsigned h01 = (c.x & 0xffffu) | (c.y << 16);
  unsigned h23 = (c.z & 0xffffu) | (c.w << 16);
  unsigned l01 = (c.x >> 16) | (c.y & 0xffff0000u);
  unsigned l23 = (c.z >> 16) | (c.w & 0xffff0000u);
  uint2 hh = {h01, h23}, ll = {l01, l23};
  *(uint2*)ph = hh; *(uint2*)pl = ll;
}
__device__ __forceinline__ void conv8_wr(float4 a, float4 b, f16* ph, f16* pl) {
  f16x8v h, l;
  h[0]=(f16)a.x; h[1]=(f16)a.y; h[2]=(f16)a.z; h[3]=(f16)a.w;
  h[4]=(f16)b.x; h[5]=(f16)b.y; h[6]=(f16)b.z; h[7]=(f16)b.w;
  l[0]=(f16)(a.x-(float)h[0]); l[1]=(f16)(a.y-(float)h[1]);
  l[2]=(f16)(a.z-(float)h[2]); l[3]=(f16)(a.w-(float)h[3]);
  l[4]=(f16)(b.x-(float)h[4]); l[5]=(f16)(b.y-(float)h[5]);
  l[6]=(f16)(b.z-(float)h[6]); l[7]=(f16)(b.w-(float)h[7]);
  *(f16x8v*)ph = h; *(f16x8v*)pl = l;
}

__global__ __launch_bounds__(NTHR, 1) void lstm_k(
    const float* __restrict__ X,  const float* __restrict__ Wx,
    const float* __restrict__ Wh, const float* __restrict__ Bg,
    const float* __restrict__ W1, const float* __restrict__ B1,
    const float* __restrict__ LNG, const float* __restrict__ LNB,
    const float* __restrict__ W2, const float* __restrict__ B2,
    float* __restrict__ Y,
    unsigned* __restrict__ FH, unsigned* __restrict__ FZ,
    unsigned* __restrict__ HBp, float* __restrict__ ZB)
{
  // LDS ~73KB
  __shared__ f16   A_hi[16][392];     // [row][k]: 0..127 x(t), 128..383 h(t-1)
  __shared__ f16   A_lo[16][392];
  __shared__ float fm_w[4][16][20];   // wave-PRIVATE fm tile [wv][col16][row16+pad]
  __shared__ float hst[16][260];      // decoder f32 staging
  __shared__ float w1_lds[16][268];   // W1 slice transposed [zc][k]
  __shared__ float w2_lds[8][268];    // W2 slice transposed [yc][k]
  __shared__ float lng_lds[256], lnb_lds[256];
  __shared__ float ln_mu[16], ln_rs[16];

  const int tid = threadIdx.x;
  const int wg  = blockIdx.x;
  const int g   = wg & 15;        // group (co-XCD X locality: wg ≡ g mod 16)
  const int jm  = wg >> 4;        // member 0..15; owns h-cols [16jm, 16jm+16)
  const int n0  = g * 16;
  const int k0  = jm * 16;
  unsigned* FHg = FH + g * 256;   // [16 WG][16 u32] = 1KB per group
  unsigned* FZg = FZ + g * 256;

  const int l     = tid & 63;
  const int wv    = __builtin_amdgcn_readfirstlane(tid >> 6);
  const int arow  = l & 15;           // A-frag row
  const int krow0 = (l >> 4) * 8;     // k octet within 32-k tile

  // Wave wv owns h-cols [k0+4wv, +4) x 4 quadrants (16 fm cols).
  const int qq = (l >> 2) & 3;        // quadrant of this lane's B column
  const int hc = l & 3;               // h-col within wave's 4
  const int ch = k0 + 4 * wv + hc;    // global h column
  unsigned* myFH = FHg + jm * 16 + wv;
  unsigned* myFZ = FZg + jm * 16 + wv;

  // ---- B fragments (quadrant-interleaved cols), f16 hi/lo, 12 k-tiles ----
  f16x8v Bh[12], Bl[12];
  {
    const int bcol = qq * 256 + ch;
    #pragma unroll
    for (int kt = 0; kt < 12; ++kt) {
      #pragma unroll
      for (int j = 0; j < 8; ++j) {
        int k = kt * 32 + krow0 + j;
        float v = (kt < 4) ? Wx[k * 1024 + bcol] : Wh[(k - 128) * 1024 + bcol];
        f16 hi = (f16)v;
        Bh[kt][j] = hi;
        Bl[kt][j] = (f16)(v - (float)hi);
      }
    }
  }

  // ---- head weights / LN params ----
  for (int idx = tid; idx < 256 * 16; idx += NTHR) {
    int k = idx >> 4, cc = idx & 15;
    w1_lds[cc][k] = W1[k * 256 + k0 + cc];
  }
  for (int idx = tid; idx < 256 * 8; idx += NTHR) {
    int k = idx >> 3, cc = idx & 7;
    w2_lds[cc][k] = W2[k * 128 + jm * 8 + cc];
  }
  lng_lds[tid] = LNG[tid];
  lnb_lds[tid] = LNB[tid];

  const float biasI = Bg[        ch];
  const float biasF = Bg[256   + ch];
  const float biasO = Bg[512   + ch];
  const float biasG = Bg[768   + ch];
  const int   myrow = (l >> 4) * 4 + qq;   // owned cell row (bijective over wave)
  float c_reg = 0.0f;                      // cell state (myrow, ch)

  const int gr = tid >> 4, gk = tid & 15;  // decoder z/LN roles
  const float b1reg = B1[k0 + gk];
  const float b2reg = (tid < 128) ? B2[jm * 8 + (tid & 7)] : 0.0f;

  // ---- prologue: x(0) into A, h region zeroed ----
  {
    const float* xp = X + (size_t)(n0 + (tid >> 4)) * 131072 + (size_t)(tid & 15) * 8;
    conv8_wr(*(const float4*)xp, *(const float4*)(xp + 4),
             &A_hi[tid >> 4][(tid & 15) * 8], &A_lo[tid >> 4][(tid & 15) * 8]);
    f16x8v z8 = {0,0,0,0,0,0,0,0};
    *(f16x8v*)&A_hi[tid >> 4][128 + (tid & 15) * 16]     = z8;
    *(f16x8v*)&A_hi[tid >> 4][128 + (tid & 15) * 16 + 8] = z8;
    *(f16x8v*)&A_lo[tid >> 4][128 + (tid & 15) * 16]     = z8;
    *(f16x8v*)&A_lo[tid >> 4][128 + (tid & 15) * 16 + 8] = z8;
  }
  __syncthreads();

  // stage packed h (16 x 256 u32) into A h-region; 64B/thread
  auto stage_hA = [&](const unsigned* hb) {
    const int row = tid >> 4, cb = (tid & 15) * 16;
    uint4 c0, c1, c2, c3;
    ld64u_sc(hb + (size_t)row * 256 + cb, c0, c1, c2, c3);
    unpack_wr(c0, &A_hi[row][128 + cb],      &A_lo[row][128 + cb]);
    unpack_wr(c1, &A_hi[row][128 + cb + 4],  &A_lo[row][128 + cb + 4]);
    unpack_wr(c2, &A_hi[row][128 + cb + 8],  &A_lo[row][128 + cb + 8]);
    unpack_wr(c3, &A_hi[row][128 + cb + 12], &A_lo[row][128 + cb + 12]);
  };

  // ================= ENCODER (t = 0..1023) =================
  for (int t = 0; t < 1024; ++t) {
    float4 xa, xb;
    if (t < 1023) {   // prefetch x(t+1) (plain cached loads)
      const float* xp = X + (size_t)(n0 + (tid >> 4)) * 131072
                          + (size_t)(t + 1) * 128 + (size_t)(tid & 15) * 8;
      xa = *(const float4*)xp;
      xb = *(const float4*)(xp + 4);
    }

    // ---- x-part: kt 0..3 (independent of h(t-1)) ----
    f32x4v ac0 = {0,0,0,0}, ac1 = {0,0,0,0}, ac2 = {0,0,0,0};
    {
      f16x8v xh[4], xl[4];
      const f16* pah = &A_hi[arow][krow0];
      const f16* pal = &A_lo[arow][krow0];
      #pragma unroll
      for (int kt = 0; kt < 4; ++kt) {
        xh[kt] = *(const f16x8v*)(pah + kt * 32);
        xl[kt] = *(const f16x8v*)(pal + kt * 32);
      }
      #pragma unroll
      for (int kt = 0; kt < 4; ++kt) {
        ac0 = __builtin_amdgcn_mfma_f32_16x16x32_f16(xh[kt], Bh[kt], ac0, 0, 0, 0);
        ac1 = __builtin_amdgcn_mfma_f32_16x16x32_f16(xh[kt], Bl[kt], ac1, 0, 0, 0);
        ac2 = __builtin_amdgcn_mfma_f32_16x16x32_f16(xl[kt], Bh[kt], ac2, 0, 0, 0);
      }
    }

    // ---- wait for all 64 producer-wave flags, stage h(t-1) ----
    if (t > 0) {
      if (wv == 0) poll_flags(FHg, (unsigned)t);
      __syncthreads();
      stage_hA(HBp + (size_t)((t - 1) & 1) * 65536 + (size_t)n0 * 256);
      __syncthreads();
    }

    // ---- h-part: kt 4..11 ----
    {
      f16x8v hh[8], hl[8];
      const f16* pah = &A_hi[arow][128 + krow0];
      const f16* pal = &A_lo[arow][128 + krow0];
      #pragma unroll
      for (int kt = 0; kt < 8; ++kt) {
        hh[kt] = *(const f16x8v*)(pah + kt * 32);
        hl[kt] = *(const f16x8v*)(pal + kt * 32);
      }
      #pragma unroll
      for (int kt = 0; kt < 8; ++kt) {
        ac0 = __builtin_amdgcn_mfma_f32_16x16x32_f16(hh[kt], Bh[kt + 4], ac0, 0, 0, 0);
        ac1 = __builtin_amdgcn_mfma_f32_16x16x32_f16(hh[kt], Bl[kt + 4], ac1, 0, 0, 0);
        ac2 = __builtin_amdgcn_mfma_f32_16x16x32_f16(hl[kt], Bh[kt + 4], ac2, 0, 0, 0);
      }
    }

    // ---- wave-private gates; publish h + per-wave flag ----
    {
      f32x4v ac = ac0 + ac1 + ac2;
      *(f32x4v*)&fm_w[wv][l & 15][(l >> 4) * 4] = ac;
      float fi = fm_w[wv][     hc][myrow] + biasI;
      float ff = fm_w[wv][ 4 + hc][myrow] + biasF;
      float fo = fm_w[wv][ 8 + hc][myrow] + biasO;
      float fg = fm_w[wv][12 + hc][myrow] + biasG;
      float si = fsigmoid(fi), sf = fsigmoid(ff), so = fsigmoid(fo);
      float tg = ftanh_(fg);
      c_reg = c_reg * sf + si * tg;
      float hv = so * ftanh_(c_reg);
      st_sc_u(HBp + (size_t)(t & 1) * 65536 + (size_t)(n0 + myrow) * 256 + ch,
              packhl(hv));
      signal_wave(myFH, (unsigned)(t + 1));   // per-wave drain + flag
    }

    if (t < 1023)
      conv8_wr(xa, xb, &A_hi[tid >> 4][(tid & 15) * 8], &A_lo[tid >> 4][(tid & 15) * 8]);
    __syncthreads();   // orders x-region write vs next iter's x-part reads
  }

  // ---- decoder prologue: stage h(1023) (parity 1) ----
  if (wv == 0) poll_flags(FHg, 1024u);
  __syncthreads();
  stage_hA(HBp + (size_t)65536 + (size_t)n0 * 256);
  __syncthreads();

  // ================= DECODER (s = 0..31) =================
  for (int s = 0; s < 32; ++s) {
    const int t = 1024 + s;

    // fm = h @ Wh + b  (kt 4..11)
    f32x4v ac0 = {0,0,0,0}, ac1 = {0,0,0,0}, ac2 = {0,0,0,0};
    {
      f16x8v hh[8], hl[8];
      const f16* pah = &A_hi[arow][128 + krow0];
      const f16* pal = &A_lo[arow][128 + krow0];
      #pragma unroll
      for (int kt = 0; kt < 8; ++kt) {
        hh[kt] = *(const f16x8v*)(pah + kt * 32);
        hl[kt] = *(const f16x8v*)(pal + kt * 32);
      }
      #pragma unroll
      for (int kt = 0; kt < 8; ++kt) {
        ac0 = __builtin_amdgcn_mfma_f32_16x16x32_f16(hh[kt], Bh[kt + 4], ac0, 0, 0, 0);
        ac1 = __builtin_amdgcn_mfma_f32_16x16x32_f16(hh[kt], Bl[kt + 4], ac1, 0, 0, 0);
        ac2 = __builtin_amdgcn_mfma_f32_16x16x32_f16(hl[kt], Bh[kt + 4], ac2, 0, 0, 0);
      }
    }
    {  // wave-private RAW gates (reference decoder: no activations on i,f,o,g)
      f32x4v ac = ac0 + ac1 + ac2;
      *(f32x4v*)&fm_w[wv][l & 15][(l >> 4) * 4] = ac;
      float fi = fm_w[wv][     hc][myrow] + biasI;
      float ff = fm_w[wv][ 4 + hc][myrow] + biasF;
      float fo = fm_w[wv][ 8 + hc][myrow] + biasO;
      float fg = fm_w[wv][12 + hc][myrow] + biasG;
      c_reg = c_reg * ff + fi * fg;
      float hv = fo * ftanh_(c_reg);
      st_sc_u(HBp + (size_t)(t & 1) * 65536 + (size_t)(n0 + myrow) * 256 + ch,
              packhl(hv));
      signal_wave(myFH, (unsigned)(t + 1));
    }

    if (wv == 0) poll_flags(FHg, (unsigned)(t + 1));
    __syncthreads();
    {  // stage h(t): packed -> A (next fm) AND f32 -> hst (z input)
      const int row = tid >> 4, cb = (tid & 15) * 16;
      const unsigned* hb = HBp + (size_t)(t & 1) * 65536 + (size_t)n0 * 256
                               + (size_t)row * 256 + cb;
      uint4 c0, c1, c2, c3;
      ld64u_sc(hb, c0, c1, c2, c3);
      unpack_wr(c0, &A_hi[row][128 + cb],      &A_lo[row][128 + cb]);
      unpack_wr(c1, &A_hi[row][128 + cb + 4],  &A_lo[row][128 + cb + 4]);
      unpack_wr(c2, &A_hi[row][128 + cb + 8],  &A_lo[row][128 + cb + 8]);
      unpack_wr(c3, &A_hi[row][128 + cb + 12], &A_lo[row][128 + cb + 12]);
      float4 f0 = {unpackf(c0.x), unpackf(c0.y), unpackf(c0.z), unpackf(c0.w)};
      float4 f1 = {unpackf(c1.x), unpackf(c1.y), unpackf(c1.z), unpackf(c1.w)};
      float4 f2 = {unpackf(c2.x), unpackf(c2.y), unpackf(c2.z), unpackf(c2.w)};
      float4 f3 = {unpackf(c3.x), unpackf(c3.y), unpackf(c3.z), unpackf(c3.w)};
      *(float4*)&hst[row][cb]      = f0;
      *(float4*)&hst[row][cb + 4]  = f1;
      *(float4*)&hst[row][cb + 8]  = f2;
      *(float4*)&hst[row][cb + 12] = f3;
    }
    __syncthreads();

    {  // z[gr][k0+gk] = h(t)[gr] . W1[:,k0+gk] + b1 ; publish + flag
      float za = b1reg;
      const float* hr = &hst[gr][0];
      const float* wr = &w1_lds[gk][0];
      #pragma unroll 4
      for (int kc = 0; kc < 64; ++kc) {
        float4 h4 = *(const float4*)(hr + kc * 4);
        float4 w4 = *(const float4*)(wr + kc * 4);
        za = fmaf(h4.x, w4.x, fmaf(h4.y, w4.y, fmaf(h4.z, w4.z, fmaf(h4.w, w4.w, za))));
      }
      st_sc_f(ZB + (size_t)(n0 + gr) * 256 + k0 + gk, za);
      signal_wave(myFZ, (unsigned)(s + 1));
    }

    if (wv == 0) poll_flags(FZg, (unsigned)(s + 1));
    __syncthreads();
    {  // stage z -> hst (all peers flagged => their hst h-reads retired)
      const float* zs = ZB + (size_t)n0 * 256 + (size_t)tid * 4;
      float4 v0, v1, v2, v3;
      ld4f_sc(zs, v0, v1, v2, v3);
      const int w0 = tid >> 6, cl = (tid & 63) * 4;
      *(float4*)&hst[w0     ][cl] = v0;
      *(float4*)&hst[w0 + 4 ][cl] = v1;
      *(float4*)&hst[w0 + 8 ][cl] = v2;
      *(float4*)&hst[w0 + 12][cl] = v3;
    }
    __syncthreads();

    {  // LayerNorm stats
      const float* zr = &hst[gr][0];
      float s1 = 0.f, s2 = 0.f;
      #pragma unroll
      for (int u = 0; u < 16; ++u) { float v = zr[gk * 16 + u]; s1 += v; s2 += v * v; }
      #pragma unroll
      for (int d = 1; d < 16; d <<= 1) { s1 += __shfl_xor(s1, d); s2 += __shfl_xor(s2, d); }
      float mu = s1 * (1.0f / 256.0f);
      float var = s2 * (1.0f / 256.0f) - mu * mu;
      float rstd = rsqrtf(var + 1e-5f);
      if (gk == 0) { ln_mu[gr] = mu; ln_rs[gr] = rstd; }
    }
    __syncthreads();

    #pragma unroll
    for (int rep = 0; rep < 4; ++rep) {  // normalize + affine + relu in place
      int f = tid + 256 * rep, r = f >> 6, kq = f & 63;
      float mu = ln_mu[r], rs = ln_rs[r];
      float4 v = *(float4*)&hst[r][kq * 4];
      int cb = kq * 4;
      v.x = fmaxf(fmaf((v.x - mu) * rs, lng_lds[cb    ], lnb_lds[cb    ]), 0.f);
      v.y = fmaxf(fmaf((v.y - mu) * rs, lng_lds[cb + 1], lnb_lds[cb + 1]), 0.f);
      v.z = fmaxf(fmaf((v.z - mu) * rs, lng_lds[cb + 2], lnb_lds[cb + 2]), 0.f);
      v.w = fmaxf(fmaf((v.w - mu) * rs, lng_lds[cb + 3], lnb_lds[cb + 3]), 0.f);
      *(float4*)&hst[r][kq * 4] = v;
    }
    __syncthreads();

    if (tid < 128) {  // y[r][jm*8+yc] = relu(zn)[r] . W2[:,jm*8+yc] + b2
      int r = tid >> 3, yc = tid & 7;
      float ya = b2reg;
      const float* zr = &hst[r][0];
      const float* wr = &w2_lds[yc][0];
      #pragma unroll 4
      for (int kc = 0; kc < 64; ++kc) {
        float4 z4 = *(const float4*)(zr + kc * 4);
        float4 w4 = *(const float4*)(wr + kc * 4);
        ya = fmaf(z4.x, w4.x, fmaf(z4.y, w4.y, fmaf(z4.z, w4.z, fmaf(z4.w, w4.w, ya))));
      }
      Y[(size_t)(n0 + r) * 4096 + (size_t)s * 128 + jm * 8 + yc] = ya;
    }
    __syncthreads();   // hst/A safe before next iteration
  }
}

extern "C" void kernel_launch(void* const* d_in, const int* in_sizes, int n_in,
                              void* d_out, int out_size, void* d_ws, size_t ws_size,
                              hipStream_t stream) {
  const float* X   = (const float*)d_in[0];
  const float* Wx  = (const float*)d_in[1];
  const float* Wh  = (const float*)d_in[2];
  const float* b   = (const float*)d_in[3];
  const float* W1  = (const float*)d_in[4];
  const float* b1  = (const float*)d_in[5];
  const float* lng = (const float*)d_in[6];
  const float* lnb = (const float*)d_in[7];
  const float* W2  = (const float*)d_in[8];
  const float* b2  = (const float*)d_in[9];
  float* Y = (float*)d_out;

  // ws layout (bytes):
  //  [0,16384)       FH   h flags [16 groups][16 WG][16 u32] (64B per WG)
  //  [16384,32768)   FZ   z flags (same layout)
  //  [32768,+512KB)  HBp  packed h double buffer [2][256][256] u32
  //  then 256KB      ZB   z buffer [256][256] f32
  unsigned* FH  = (unsigned*)d_ws;
  unsigned* FZ  = (unsigned*)((char*)d_ws + 16384);
  unsigned* HBp = (unsigned*)((char*)d_ws + 32768);
  float*    ZB  = (float*)((char*)d_ws + 32768 + 524288);
  (void)in_sizes; (void)n_in; (void)out_size; (void)ws_size;

  hipMemsetAsync(d_ws, 0, 32768, stream);   // clear flags each launch
  hipLaunchKernelGGL(lstm_k, dim3(256), dim3(NTHR), 0, stream,
                     X, Wx, Wh, b, W1, b1, lng, lnb, W2, b2, Y, FH, FZ, HBp, ZB);
}